// Round 6
// baseline (228.010 us; speedup 1.0000x reference)
//
#include <hip/hip_runtime.h>
#include <hip/hip_bf16.h>

typedef __bf16 bf16_t;
typedef __bf16 bf16x8 __attribute__((ext_vector_type(8)));
typedef __bf16 bf16x4 __attribute__((ext_vector_type(4)));
typedef float  f32x4  __attribute__((ext_vector_type(4)));

#define MFMA16(a, b, c) __builtin_amdgcn_mfma_f32_16x16x32_bf16((a), (b), (c), 0, 0, 0)

constexpr int E  = 1024;
constexpr int S  = 2048;
constexpr int H  = 16;
constexpr int M  = 4096;  // B*S

// ---------------------------------------------------------------------------
// async global->LDS 16B (wave-uniform LDS base + lane*16)
// ---------------------------------------------------------------------------
__device__ __forceinline__ void glds16(const bf16_t* src, bf16_t* dst) {
  __builtin_amdgcn_global_load_lds(
      (const __attribute__((address_space(1))) void*)src,
      (__attribute__((address_space(3))) void*)dst, 16, 0, 0);
}

// Stage a [ROWS x 64] bf16 tile (global row stride gld) into LDS, XOR-swizzled:
// LDS 16B-chunk (row, cs) holds global 8-elem chunk (cs ^ (row&7)) of that row.
// NT = block thread count (multiple of 64).
template <int ROWS, int NT>
__device__ __forceinline__ void stage_tile(const bf16_t* g, int gld,
                                           bf16_t* lds, int tid) {
  const int w = tid >> 6, l = tid & 63;
#pragma unroll
  for (int i = 0; i < ROWS * 8 / NT; ++i) {  // ROWS*8 chunks / NT threads
    const int c = i * NT + w * 64 + l;
    const int row = c >> 3;
    const int gch = (c & 7) ^ (row & 7);
    glds16(g + (size_t)row * gld + gch * 8, lds + (size_t)(i * NT + w * 64) * 8);
  }
}

// Read an 8-elem k-chunk (kc in [0,8)) of row `row` from a swizzled tile.
__device__ __forceinline__ bf16x8 read_frag(const bf16_t* lds, int row, int kc) {
  return *(const bf16x8*)(lds + (size_t)((row << 3) + (kc ^ (row & 7))) * 8);
}

// ---------------------------------------------------------------------------
// fused fp32->bf16 conversion for x + 4 weight matrices
// ---------------------------------------------------------------------------
__global__ void cvt_all_kernel(const float* __restrict__ x,
                               const float* __restrict__ w0, const float* __restrict__ w1,
                               const float* __restrict__ w2, const float* __restrict__ w3,
                               bf16_t* __restrict__ xb,
                               bf16_t* __restrict__ o0, bf16_t* __restrict__ o1,
                               bf16_t* __restrict__ o2, bf16_t* __restrict__ o3) {
  const int bid = blockIdx.x;
  const float* s;
  bf16_t* d;
  int idx;
  if (bid < 4096) {
    s = x; d = xb; idx = bid * 256 + threadIdx.x;
  } else {
    const int seg = (bid - 4096) >> 10;
    s = seg == 0 ? w0 : seg == 1 ? w1 : seg == 2 ? w2 : w3;
    d = seg == 0 ? o0 : seg == 1 ? o1 : seg == 2 ? o2 : o3;
    idx = ((bid - 4096) & 1023) * 256 + threadIdx.x;
  }
  float4 v = ((const float4*)s)[idx];
  bf16x4 o;
  o[0] = (bf16_t)v.x; o[1] = (bf16_t)v.y; o[2] = (bf16_t)v.z; o[3] = (bf16_t)v.w;
  ((bf16x4*)d)[idx] = o;
}

// ---------------------------------------------------------------------------
// m97-style GEMM core: 128x128 tile, BK=64, global_load_lds staging.
// ---------------------------------------------------------------------------
__device__ __forceinline__ void gemm_core(const bf16_t* __restrict__ A,
                                          const bf16_t* __restrict__ W, int Kd,
                                          bf16_t* As, bf16_t* Bs, int tid,
                                          f32x4 acc[4][4]) {
  const int w = tid >> 6, l = tid & 63;
  const int lq = l & 15, qd = l >> 4;
  const int wr = (w >> 1) * 64, wc = (w & 1) * 64;
#pragma unroll
  for (int i = 0; i < 4; ++i)
#pragma unroll
    for (int j = 0; j < 4; ++j) acc[i][j] = (f32x4){0.f, 0.f, 0.f, 0.f};

  const int KT = Kd / 64;
  for (int kt = 0; kt < KT; ++kt) {
    __syncthreads();
    stage_tile<128, 256>(A + kt * 64, Kd, As, tid);
    stage_tile<128, 256>(W + kt * 64, Kd, Bs, tid);
    __syncthreads();
#pragma unroll
    for (int ks = 0; ks < 2; ++ks) {
      bf16x8 af[4], bw[4];
#pragma unroll
      for (int mi = 0; mi < 4; ++mi)
        af[mi] = read_frag(As, wr + mi * 16 + lq, ks * 4 + qd);
#pragma unroll
      for (int ni = 0; ni < 4; ++ni)
        bw[ni] = read_frag(Bs, wc + ni * 16 + lq, ks * 4 + qd);
#pragma unroll
      for (int mi = 0; mi < 4; ++mi)
#pragma unroll
        for (int ni = 0; ni < 4; ++ni)
          acc[mi][ni] = MFMA16(af[mi], bw[ni], acc[mi][ni]);
    }
  }
}

// ---------------------------------------------------------------------------
// fused QKV projection. grid (24, 32). All outputs row-major [4096,1024] bf16.
// Q PRE-SCALED by log2(e)/sqrt(Dh) (folds softmax scale).
// ---------------------------------------------------------------------------
__global__ __launch_bounds__(256) void qkv_gemm_kernel(
    const bf16_t* __restrict__ xb,
    const bf16_t* __restrict__ wq, const bf16_t* __restrict__ wk,
    const bf16_t* __restrict__ wv,
    const float* __restrict__ bq, const float* __restrict__ bk,
    const float* __restrict__ bv,
    bf16_t* __restrict__ Qb, bf16_t* __restrict__ Kb, bf16_t* __restrict__ Vb) {
  __shared__ __align__(16) bf16_t As[128 * 64];
  __shared__ __align__(16) bf16_t Bs[128 * 64];
  const int tid = threadIdx.x;
  const int which = blockIdx.x >> 3;
  const int n0 = (blockIdx.x & 7) * 128;
  const int m0 = blockIdx.y * 128;
  const bf16_t* Wp = which == 0 ? wq : which == 1 ? wk : wv;
  const float* bp  = which == 0 ? bq : which == 1 ? bk : bv;
  bf16_t* Out      = which == 0 ? Qb : which == 1 ? Kb : Vb;
  const float sc = (which == 0) ? (1.4426950408889634f * 0.125f) : 1.0f;

  f32x4 acc[4][4];
  gemm_core(xb + (size_t)m0 * E, Wp + (size_t)n0 * E, E, As, Bs, tid, acc);

  const int w = tid >> 6, l = tid & 63, lq = l & 15, qd = l >> 4;
  const int wr = (w >> 1) * 64, wc = (w & 1) * 64;
#pragma unroll
  for (int ni = 0; ni < 4; ++ni) {
    const int col = n0 + wc + ni * 16 + lq;
    const float bvv = bp[col];
#pragma unroll
    for (int mi = 0; mi < 4; ++mi)
#pragma unroll
      for (int r = 0; r < 4; ++r) {
        const int row = m0 + wr + mi * 16 + qd * 4 + r;
        Out[(size_t)row * E + col] = (bf16_t)((acc[mi][ni][r] + bvv) * sc);
      }
  }
}

// ---------------------------------------------------------------------------
// V transpose: Vb [4096,1024] row-major -> VT[bh][d][s] with keys
// sigma-permuted within each 64-block: VT[bh][d][64*blk+p] = V[64*blk+sigma(p)][d],
// sigma(p) = (p&3)*16 + (p>>2).  Grid (32 s-tiles, 32 bh) x 256 thr.
// Tile = 64 s-rows x 64 d = 512 8-elem chunks; 2 chunks/thread each phase.
// ---------------------------------------------------------------------------
__global__ __launch_bounds__(256) void vtrans_kernel(const bf16_t* __restrict__ Vb,
                                                     bf16_t* __restrict__ VT) {
  constexpr int LDT = 72;
  __shared__ __align__(16) bf16_t T[64 * LDT];  // T[p][d] = V[s0+sigma(p)][d]
  const int tid = threadIdx.x;
  const int st = blockIdx.x, bh = blockIdx.y;
  const int b = bh >> 4, h = bh & 15;
  const int s0 = st * 64;
  const size_t rowbase = (size_t)b * S;

  // read phase: chunk c -> source row s0+sl (sl = c>>3), d-part dp = c&7
#pragma unroll
  for (int i = 0; i < 2; ++i) {
    const int c = i * 256 + tid;
    const int sl = c >> 3, dp = c & 7;
    const int p = (sl & 15) * 4 + (sl >> 4);   // sigma^-1(sl)
    bf16x8 v = *(const bf16x8*)(Vb + (rowbase + s0 + sl) * E + h * 64 + dp * 8);
    *(bf16x8*)&T[p * LDT + dp * 8] = v;
  }
  __syncthreads();
  // write phase: chunk c -> out row d = c>>3, positions pp = (c&7)*8 .. +8
#pragma unroll
  for (int i = 0; i < 2; ++i) {
    const int c = i * 256 + tid;
    const int d = c >> 3, pp = (c & 7) * 8;
    bf16x8 o;
#pragma unroll
    for (int j = 0; j < 8; ++j) o[j] = T[(pp + j) * LDT + d];
    *(bf16x8*)&VT[((size_t)bh * 64 + d) * S + s0 + pp] = o;
  }
}

// ---------------------------------------------------------------------------
// output projection: [4096,1024] bf16 x wo^T + bo -> fp32
// ---------------------------------------------------------------------------
__global__ __launch_bounds__(256) void oproj_gemm_kernel(
    const bf16_t* __restrict__ Ob, const bf16_t* __restrict__ wo,
    const float* __restrict__ bo, float* __restrict__ out) {
  __shared__ __align__(16) bf16_t As[128 * 64];
  __shared__ __align__(16) bf16_t Bs[128 * 64];
  const int tid = threadIdx.x;
  const int n0 = blockIdx.x * 128;
  const int m0 = blockIdx.y * 128;
  f32x4 acc[4][4];
  gemm_core(Ob + (size_t)m0 * E, wo + (size_t)n0 * E, E, As, Bs, tid, acc);
  const int w = tid >> 6, l = tid & 63, lq = l & 15, qd = l >> 4;
  const int wr = (w >> 1) * 64, wc = (w & 1) * 64;
#pragma unroll
  for (int ni = 0; ni < 4; ++ni) {
    const int col = n0 + wc + ni * 16 + lq;
    const float bvv = bo[col];
#pragma unroll
    for (int mi = 0; mi < 4; ++mi)
#pragma unroll
      for (int r = 0; r < 4; ++r) {
        const int row = m0 + wr + mi * 16 + qd * 4 + r;
        out[(size_t)row * E + col] = acc[mi][ni][r] + bvv;
      }
  }
}

// ---------------------------------------------------------------------------
// causal flash attention v5b: SINGLE-WAVE blocks (64 thr), 32 q-rows per wave,
// 32-row q-tiles -> grid 2048 = 64 q-tiles x 32 bh. LDS ~21 KB/block -> 7
// blocks (7 independent waves) per CU; heavy-first (qt = 63 - qi).
// Explicit s_waitcnt vmcnt(0) after DMA staging: with single-wave workgroups
// the s_barrier (and its implied waitcnt insertion point) may be elided, and
// ds_read of DMA-written LDS has no register dependency to track.
// No-max softmax (Q pre-scaled), sigma-permuted P/V key order for packed b64
// P stores, K/V frags shared across the wave's two 16-row m-tiles.
// ---------------------------------------------------------------------------
__global__ __launch_bounds__(64) void attn_kernel(
    const bf16_t* __restrict__ Q, const bf16_t* __restrict__ K,
    const bf16_t* __restrict__ VT, bf16_t* __restrict__ O) {
  constexpr int LDP = 72;  // halfwords; 144 B rows (16B-aligned)
  __shared__ __align__(16) bf16_t Ks[64 * 64];   // swizzled [key][d]
  __shared__ __align__(16) bf16_t Vt[64 * 64];   // swizzled [d][perm-key]
  __shared__ __align__(16) bf16_t Ps[32 * LDP];  // P [qrow][perm-key]

  const int tid = threadIdx.x;
  const int l = tid & 63;
  const int lq = l & 15, qd = l >> 4;
  const int bi = blockIdx.x;
  const int qi = bi >> 5;
  const int qt = 63 - qi;           // heavy-first
  const int bh = bi & 31;
  const int b = bh >> 4, h = bh & 15;
  const int qr = qt * 32;           // wave rows [qr, qr+32)
  const size_t rowbase = (size_t)b * S;
  const size_t vtbase = (size_t)bh * 64 * S;

  // Q fragments (pre-scaled): aq[mi][ks], rows qr + mi*16 + lq
  bf16x8 aq[2][2];
#pragma unroll
  for (int mi = 0; mi < 2; ++mi)
#pragma unroll
    for (int ks = 0; ks < 2; ++ks)
      aq[mi][ks] = *(const bf16x8*)(Q + (rowbase + qr + mi * 16 + lq) * E +
                                    h * 64 + ks * 32 + qd * 8);

  f32x4 oacc[2][4];
#pragma unroll
  for (int mi = 0; mi < 2; ++mi)
#pragma unroll
    for (int nt = 0; nt < 4; ++nt) oacc[mi][nt] = (f32x4){0.f, 0.f, 0.f, 0.f};
  float rs[2][4] = {{0.f, 0.f, 0.f, 0.f}, {0.f, 0.f, 0.f, 0.f}};

  const int KT = (qt >> 1) + 1;
  for (int kt = 0; kt < KT; ++kt) {
    const int k0 = kt * 64;
    __syncthreads();  // single-wave: prior ds_reads already drained via MFMA use
    stage_tile<64, 64>(K + (rowbase + k0) * E + h * 64, E, Ks, tid);
    stage_tile<64, 64>(VT + vtbase + k0, S, Vt, tid);
    asm volatile("s_waitcnt vmcnt(0)" ::: "memory");  // DMA resident (barrier may be elided)
    __syncthreads();

    const bool needmask = (k0 + 63 > qr);
    // ---- QK^T: 16 MFMA, K-frags shared across mi ----
    f32x4 sacc[2][4];
#pragma unroll
    for (int mi = 0; mi < 2; ++mi)
#pragma unroll
      for (int nt = 0; nt < 4; ++nt) sacc[mi][nt] = (f32x4){0.f, 0.f, 0.f, 0.f};
#pragma unroll
    for (int ks = 0; ks < 2; ++ks) {
      bf16x8 bk[4];
#pragma unroll
      for (int nt = 0; nt < 4; ++nt)
        bk[nt] = read_frag(Ks, nt * 16 + lq, ks * 4 + qd);
#pragma unroll
      for (int mi = 0; mi < 2; ++mi)
#pragma unroll
        for (int nt = 0; nt < 4; ++nt)
          sacc[mi][nt] = MFMA16(aq[mi][ks], bk[nt], sacc[mi][nt]);
    }
    // ---- softmax (no-max, pre-scaled) + packed b64 P stores ----
#pragma unroll
    for (int mi = 0; mi < 2; ++mi)
#pragma unroll
      for (int r = 0; r < 4; ++r) {
        bf16x4 pk;
#pragma unroll
        for (int nt = 0; nt < 4; ++nt) {
          float pv = exp2f(sacc[mi][nt][r]);
          if (needmask) {
            const int kg = k0 + nt * 16 + lq;
            const int qg = qr + mi * 16 + qd * 4 + r;
            pv = (kg > qg) ? 0.f : pv;
          }
          rs[mi][r] += pv;
          pk[nt] = (bf16_t)pv;
        }
        *(bf16x4*)&Ps[(mi * 16 + qd * 4 + r) * LDP + lq * 4] = pk;
      }
    // ---- PV: 16 MFMA, V-frags shared across mi ----
    bf16x8 ap[2][2];
#pragma unroll
    for (int mi = 0; mi < 2; ++mi)
#pragma unroll
      for (int ks = 0; ks < 2; ++ks)
        ap[mi][ks] = *(const bf16x8*)&Ps[(mi * 16 + lq) * LDP + ks * 32 + qd * 8];
#pragma unroll
    for (int ks = 0; ks < 2; ++ks) {
      bf16x8 bv[4];
#pragma unroll
      for (int nt = 0; nt < 4; ++nt)
        bv[nt] = read_frag(Vt, nt * 16 + lq, ks * 4 + qd);
#pragma unroll
      for (int mi = 0; mi < 2; ++mi)
#pragma unroll
        for (int nt = 0; nt < 4; ++nt)
          oacc[mi][nt] = MFMA16(ap[mi][ks], bv[nt], oacc[mi][nt]);
    }
  }

  // deferred row-sum reduce + O write
#pragma unroll
  for (int mi = 0; mi < 2; ++mi) {
    float rinv[4];
#pragma unroll
    for (int r = 0; r < 4; ++r) {
      float t = rs[mi][r];
      t += __shfl_xor(t, 1);
      t += __shfl_xor(t, 2);
      t += __shfl_xor(t, 4);
      t += __shfl_xor(t, 8);
      rinv[r] = 1.0f / t;
    }
#pragma unroll
    for (int nt = 0; nt < 4; ++nt)
#pragma unroll
      for (int r = 0; r < 4; ++r) {
        const int qg = qr + mi * 16 + qd * 4 + r;
        O[(rowbase + qg) * E + h * 64 + nt * 16 + lq] =
            (bf16_t)(oacc[mi][nt][r] * rinv[r]);
      }
  }
}

// ---------------------------------------------------------------------------
// launch
// ---------------------------------------------------------------------------
extern "C" void kernel_launch(void* const* d_in, const int* in_sizes, int n_in,
                              void* d_out, int out_size, void* d_ws, size_t ws_size,
                              hipStream_t stream) {
  const float* x  = (const float*)d_in[0];
  const float* Wq = (const float*)d_in[1];
  const float* bq = (const float*)d_in[2];
  const float* Wk = (const float*)d_in[3];
  const float* bk = (const float*)d_in[4];
  const float* Wv = (const float*)d_in[5];
  const float* bv = (const float*)d_in[6];
  const float* Wo = (const float*)d_in[7];
  const float* bo = (const float*)d_in[8];
  float* out = (float*)d_out;

  unsigned char* ws = (unsigned char*)d_ws;
  constexpr size_t MB = 1ull << 20;
  bf16_t* xb  = (bf16_t*)(ws + 0 * MB);   // 8 MB; reused as Ob after qkv
  bf16_t* wqb = (bf16_t*)(ws + 8 * MB);
  bf16_t* wkb = (bf16_t*)(ws + 10 * MB);
  bf16_t* wvb = (bf16_t*)(ws + 12 * MB);
  bf16_t* wob = (bf16_t*)(ws + 14 * MB);
  bf16_t* Qb  = (bf16_t*)(ws + 16 * MB);
  bf16_t* Kb  = (bf16_t*)(ws + 24 * MB);
  bf16_t* Vb  = (bf16_t*)(ws + 32 * MB);  // row-major V
  bf16_t* VT  = (bf16_t*)(ws + 40 * MB);  // [32 bh][64 d][2048 s, sigma-perm per 64]
  bf16_t* Ob  = xb;                       // xb dead after qkv

  cvt_all_kernel<<<4096 + 4 * 1024, 256, 0, stream>>>(
      x, Wq, Wk, Wv, Wo, xb, wqb, wkb, wvb, wob);

  qkv_gemm_kernel<<<dim3(24, 32), 256, 0, stream>>>(
      xb, wqb, wkb, wvb, bq, bk, bv, Qb, Kb, Vb);

  vtrans_kernel<<<dim3(32, 32), 256, 0, stream>>>(Vb, VT);

  attn_kernel<<<2048, 64, 0, stream>>>(Qb, Kb, VT, Ob);

  oproj_gemm_kernel<<<dim3(8, 32), 256, 0, stream>>>(Ob, wob, bo, out);
}

// Round 7
// 210.067 us; speedup vs baseline: 1.0854x; 1.0854x over previous
//
#include <hip/hip_runtime.h>
#include <hip/hip_bf16.h>

typedef __bf16 bf16_t;
typedef __bf16 bf16x8 __attribute__((ext_vector_type(8)));
typedef __bf16 bf16x4 __attribute__((ext_vector_type(4)));
typedef float  f32x4  __attribute__((ext_vector_type(4)));

#define MFMA16(a, b, c) __builtin_amdgcn_mfma_f32_16x16x32_bf16((a), (b), (c), 0, 0, 0)

constexpr int E  = 1024;
constexpr int S  = 2048;
constexpr int H  = 16;
constexpr int M  = 4096;  // B*S

// ---------------------------------------------------------------------------
// async global->LDS 16B (wave-uniform LDS base + lane*16)
// ---------------------------------------------------------------------------
__device__ __forceinline__ void glds16(const bf16_t* src, bf16_t* dst) {
  __builtin_amdgcn_global_load_lds(
      (const __attribute__((address_space(1))) void*)src,
      (__attribute__((address_space(3))) void*)dst, 16, 0, 0);
}

// Stage a [ROWS x 64] bf16 tile (global row stride gld) into LDS, XOR-swizzled:
// LDS 16B-chunk (row, cs) holds global 8-elem chunk (cs ^ (row&7)) of that row.
template <int ROWS, int NT>
__device__ __forceinline__ void stage_tile(const bf16_t* g, int gld,
                                           bf16_t* lds, int tid) {
  const int w = tid >> 6, l = tid & 63;
#pragma unroll
  for (int i = 0; i < ROWS * 8 / NT; ++i) {
    const int c = i * NT + w * 64 + l;
    const int row = c >> 3;
    const int gch = (c & 7) ^ (row & 7);
    glds16(g + (size_t)row * gld + gch * 8, lds + (size_t)(i * NT + w * 64) * 8);
  }
}

// Read an 8-elem k-chunk (kc in [0,8)) of row `row` from a swizzled tile.
__device__ __forceinline__ bf16x8 read_frag(const bf16_t* lds, int row, int kc) {
  return *(const bf16x8*)(lds + (size_t)((row << 3) + (kc ^ (row & 7))) * 8);
}

// ---------------------------------------------------------------------------
// fused fp32->bf16 conversion for x + 4 weight matrices
// ---------------------------------------------------------------------------
__global__ void cvt_all_kernel(const float* __restrict__ x,
                               const float* __restrict__ w0, const float* __restrict__ w1,
                               const float* __restrict__ w2, const float* __restrict__ w3,
                               bf16_t* __restrict__ xb,
                               bf16_t* __restrict__ o0, bf16_t* __restrict__ o1,
                               bf16_t* __restrict__ o2, bf16_t* __restrict__ o3) {
  const int bid = blockIdx.x;
  const float* s;
  bf16_t* d;
  int idx;
  if (bid < 4096) {
    s = x; d = xb; idx = bid * 256 + threadIdx.x;
  } else {
    const int seg = (bid - 4096) >> 10;
    s = seg == 0 ? w0 : seg == 1 ? w1 : seg == 2 ? w2 : w3;
    d = seg == 0 ? o0 : seg == 1 ? o1 : seg == 2 ? o2 : o3;
    idx = ((bid - 4096) & 1023) * 256 + threadIdx.x;
  }
  float4 v = ((const float4*)s)[idx];
  bf16x4 o;
  o[0] = (bf16_t)v.x; o[1] = (bf16_t)v.y; o[2] = (bf16_t)v.z; o[3] = (bf16_t)v.w;
  ((bf16x4*)d)[idx] = o;
}

// ---------------------------------------------------------------------------
// m97-style GEMM core: 128x128 tile, BK=64, global_load_lds staging.
// ---------------------------------------------------------------------------
__device__ __forceinline__ void gemm_core(const bf16_t* __restrict__ A,
                                          const bf16_t* __restrict__ W, int Kd,
                                          bf16_t* As, bf16_t* Bs, int tid,
                                          f32x4 acc[4][4]) {
  const int w = tid >> 6, l = tid & 63;
  const int lq = l & 15, qd = l >> 4;
  const int wr = (w >> 1) * 64, wc = (w & 1) * 64;
#pragma unroll
  for (int i = 0; i < 4; ++i)
#pragma unroll
    for (int j = 0; j < 4; ++j) acc[i][j] = (f32x4){0.f, 0.f, 0.f, 0.f};

  const int KT = Kd / 64;
  for (int kt = 0; kt < KT; ++kt) {
    __syncthreads();
    stage_tile<128, 256>(A + kt * 64, Kd, As, tid);
    stage_tile<128, 256>(W + kt * 64, Kd, Bs, tid);
    __syncthreads();
#pragma unroll
    for (int ks = 0; ks < 2; ++ks) {
      bf16x8 af[4], bw[4];
#pragma unroll
      for (int mi = 0; mi < 4; ++mi)
        af[mi] = read_frag(As, wr + mi * 16 + lq, ks * 4 + qd);
#pragma unroll
      for (int ni = 0; ni < 4; ++ni)
        bw[ni] = read_frag(Bs, wc + ni * 16 + lq, ks * 4 + qd);
#pragma unroll
      for (int mi = 0; mi < 4; ++mi)
#pragma unroll
        for (int ni = 0; ni < 4; ++ni)
          acc[mi][ni] = MFMA16(af[mi], bw[ni], acc[mi][ni]);
    }
  }
}

// ---------------------------------------------------------------------------
// fused QKV projection. grid (24, 32). All outputs row-major [4096,1024] bf16.
// Q PRE-SCALED by log2(e)/sqrt(Dh) (folds softmax scale).
// ---------------------------------------------------------------------------
__global__ __launch_bounds__(256) void qkv_gemm_kernel(
    const bf16_t* __restrict__ xb,
    const bf16_t* __restrict__ wq, const bf16_t* __restrict__ wk,
    const bf16_t* __restrict__ wv,
    const float* __restrict__ bq, const float* __restrict__ bk,
    const float* __restrict__ bv,
    bf16_t* __restrict__ Qb, bf16_t* __restrict__ Kb, bf16_t* __restrict__ Vb) {
  __shared__ __align__(16) bf16_t As[128 * 64];
  __shared__ __align__(16) bf16_t Bs[128 * 64];
  const int tid = threadIdx.x;
  const int which = blockIdx.x >> 3;
  const int n0 = (blockIdx.x & 7) * 128;
  const int m0 = blockIdx.y * 128;
  const bf16_t* Wp = which == 0 ? wq : which == 1 ? wk : wv;
  const float* bp  = which == 0 ? bq : which == 1 ? bk : bv;
  bf16_t* Out      = which == 0 ? Qb : which == 1 ? Kb : Vb;
  const float sc = (which == 0) ? (1.4426950408889634f * 0.125f) : 1.0f;

  f32x4 acc[4][4];
  gemm_core(xb + (size_t)m0 * E, Wp + (size_t)n0 * E, E, As, Bs, tid, acc);

  const int w = tid >> 6, l = tid & 63, lq = l & 15, qd = l >> 4;
  const int wr = (w >> 1) * 64, wc = (w & 1) * 64;
#pragma unroll
  for (int ni = 0; ni < 4; ++ni) {
    const int col = n0 + wc + ni * 16 + lq;
    const float bvv = bp[col];
#pragma unroll
    for (int mi = 0; mi < 4; ++mi)
#pragma unroll
      for (int r = 0; r < 4; ++r) {
        const int row = m0 + wr + mi * 16 + qd * 4 + r;
        Out[(size_t)row * E + col] = (bf16_t)((acc[mi][ni][r] + bvv) * sc);
      }
  }
}

// ---------------------------------------------------------------------------
// V transpose: Vb [4096,1024] row-major -> VT[bh][d][s], keys sigma-permuted
// within each 64-block: VT[bh][d][64*blk+p] = V[64*blk+sigma(p)][d],
// sigma(p) = (p&3)*16 + (p>>2).  Grid (32 s-tiles, 32 bh) x 256 thr.
// ---------------------------------------------------------------------------
__global__ __launch_bounds__(256) void vtrans_kernel(const bf16_t* __restrict__ Vb,
                                                     bf16_t* __restrict__ VT) {
  constexpr int LDT = 72;
  __shared__ __align__(16) bf16_t T[64 * LDT];  // T[p][d] = V[s0+sigma(p)][d]
  const int tid = threadIdx.x;
  const int st = blockIdx.x, bh = blockIdx.y;
  const int b = bh >> 4, h = bh & 15;
  const int s0 = st * 64;
  const size_t rowbase = (size_t)b * S;
#pragma unroll
  for (int i = 0; i < 2; ++i) {
    const int c = i * 256 + tid;
    const int sl = c >> 3, dp = c & 7;
    const int p = (sl & 15) * 4 + (sl >> 4);   // sigma^-1(sl)
    bf16x8 v = *(const bf16x8*)(Vb + (rowbase + s0 + sl) * E + h * 64 + dp * 8);
    *(bf16x8*)&T[p * LDT + dp * 8] = v;
  }
  __syncthreads();
#pragma unroll
  for (int i = 0; i < 2; ++i) {
    const int c = i * 256 + tid;
    const int d = c >> 3, pp = (c & 7) * 8;
    bf16x8 o;
#pragma unroll
    for (int j = 0; j < 8; ++j) o[j] = T[(pp + j) * LDT + d];
    *(bf16x8*)&VT[((size_t)bh * 64 + d) * S + s0 + pp] = o;
  }
}

// ---------------------------------------------------------------------------
// output projection v2: 64x128 tiles -> grid (8, 64) = 512 blocks (2x the
// residency of the 128x128 version; oproj was 1 block/CU before).
// ---------------------------------------------------------------------------
__global__ __launch_bounds__(256) void oproj_gemm_kernel(
    const bf16_t* __restrict__ Ob, const bf16_t* __restrict__ wo,
    const float* __restrict__ bo, float* __restrict__ out) {
  __shared__ __align__(16) bf16_t As[64 * 64];    // 8 KB
  __shared__ __align__(16) bf16_t Bs[128 * 64];   // 16 KB
  const int tid = threadIdx.x;
  const int n0 = blockIdx.x * 128;
  const int m0 = blockIdx.y * 64;
  const int w = tid >> 6, l = tid & 63, lq = l & 15, qd = l >> 4;
  const int wr = (w >> 1) * 32, wc = (w & 1) * 64;

  f32x4 acc[2][4];
#pragma unroll
  for (int i = 0; i < 2; ++i)
#pragma unroll
    for (int j = 0; j < 4; ++j) acc[i][j] = (f32x4){0.f, 0.f, 0.f, 0.f};

  for (int kt = 0; kt < 16; ++kt) {
    __syncthreads();
    stage_tile<64, 256>(Ob + (size_t)m0 * E + kt * 64, E, As, tid);
    stage_tile<128, 256>(wo + (size_t)n0 * E + kt * 64, E, Bs, tid);
    __syncthreads();
#pragma unroll
    for (int ks = 0; ks < 2; ++ks) {
      bf16x8 af[2], bw[4];
#pragma unroll
      for (int mi = 0; mi < 2; ++mi)
        af[mi] = read_frag(As, wr + mi * 16 + lq, ks * 4 + qd);
#pragma unroll
      for (int ni = 0; ni < 4; ++ni)
        bw[ni] = read_frag(Bs, wc + ni * 16 + lq, ks * 4 + qd);
#pragma unroll
      for (int mi = 0; mi < 2; ++mi)
#pragma unroll
        for (int ni = 0; ni < 4; ++ni)
          acc[mi][ni] = MFMA16(af[mi], bw[ni], acc[mi][ni]);
    }
  }
#pragma unroll
  for (int ni = 0; ni < 4; ++ni) {
    const int col = n0 + wc + ni * 16 + lq;
    const float bvv = bo[col];
#pragma unroll
    for (int mi = 0; mi < 2; ++mi)
#pragma unroll
      for (int r = 0; r < 4; ++r) {
        const int row = m0 + wr + mi * 16 + qd * 4 + r;
        out[(size_t)row * E + col] = acc[mi][ni][r] + bvv;
      }
  }
}

// ---------------------------------------------------------------------------
// causal flash attention v7: PERSISTENT blocks + atomic work queue.
// 768 blocks (3/CU, all resident: ~25.7 KB LDS, ~96 VGPR) x 256 thr (4 waves
// x 16 q-rows = 64-row q-tile per item). 1024 items = 32 qt x 32 bh, heavy
// qt first (qt = 31 - item/32); early finishers steal remaining items ->
// sustained ~12 waves/CU and automatic load balance.
// No-max softmax (Q pre-scaled by log2e/8), sigma-permuted P/V key order for
// packed b64 P stores.
// ---------------------------------------------------------------------------
__global__ __launch_bounds__(256, 3) void attn_kernel(
    const bf16_t* __restrict__ Q, const bf16_t* __restrict__ K,
    const bf16_t* __restrict__ VT, bf16_t* __restrict__ O,
    unsigned int* __restrict__ counter) {
  constexpr int LDP = 72;
  __shared__ __align__(16) bf16_t Ks[64 * 64];      // swizzled [key][d]
  __shared__ __align__(16) bf16_t Vt[64 * 64];      // swizzled [d][perm-key]
  __shared__ __align__(16) bf16_t Ps[4][16 * LDP];  // per-wave P [qrow][perm-key]
  __shared__ int item_sh;

  const int tid = threadIdx.x;
  const int w = tid >> 6, l = tid & 63;
  const int lq = l & 15, qd = l >> 4;

  for (;;) {
    if (tid == 0) item_sh = (int)atomicAdd(counter, 1u);
    __syncthreads();
    const int item = item_sh;
    if (item >= 1024) break;  // uniform exit
    const int qt = 31 - (item >> 5);  // heavy first
    const int bh = item & 31;
    const int b = bh >> 4, h = bh & 15;
    const int q0 = qt * 64;
    const int qr = q0 + w * 16;  // wave rows [qr, qr+16)
    const size_t rowbase = (size_t)b * S;
    const size_t vtbase = (size_t)bh * 64 * S;

    // Q fragments (pre-scaled): rows qr+lq, k = ks*32 + qd*8
    bf16x8 aq[2];
#pragma unroll
    for (int ks = 0; ks < 2; ++ks)
      aq[ks] = *(const bf16x8*)(Q + (rowbase + qr + lq) * E + h * 64 + ks * 32 + qd * 8);

    f32x4 oacc[4];
#pragma unroll
    for (int nt = 0; nt < 4; ++nt) oacc[nt] = (f32x4){0.f, 0.f, 0.f, 0.f};
    float rs[4] = {0.f, 0.f, 0.f, 0.f};

    for (int kt = 0; kt <= qt; ++kt) {
      const int k0 = kt * 64;
      __syncthreads();  // prev iter's Ks/Vt reads done (also guards item_sh reuse)
      stage_tile<64, 256>(K + (rowbase + k0) * E + h * 64, E, Ks, tid);
      stage_tile<64, 256>(VT + vtbase + k0, S, Vt, tid);
      __syncthreads();  // tiles resident (vmcnt drained before barrier)

      const bool needmask = (k0 + 63 > qr);
      // ---- QK^T: 8 MFMA ----
      f32x4 sacc[4];
#pragma unroll
      for (int nt = 0; nt < 4; ++nt) sacc[nt] = (f32x4){0.f, 0.f, 0.f, 0.f};
#pragma unroll
      for (int ks = 0; ks < 2; ++ks) {
        bf16x8 bk[4];
#pragma unroll
        for (int nt = 0; nt < 4; ++nt)
          bk[nt] = read_frag(Ks, nt * 16 + lq, ks * 4 + qd);
#pragma unroll
        for (int nt = 0; nt < 4; ++nt)
          sacc[nt] = MFMA16(aq[ks], bk[nt], sacc[nt]);
      }
      // ---- softmax (no-max, pre-scaled) + packed b64 P stores ----
#pragma unroll
      for (int r = 0; r < 4; ++r) {
        bf16x4 pk;
#pragma unroll
        for (int nt = 0; nt < 4; ++nt) {
          float pv = exp2f(sacc[nt][r]);
          if (needmask) {
            const int kg = k0 + nt * 16 + lq;
            const int qg = qr + qd * 4 + r;
            pv = (kg > qg) ? 0.f : pv;
          }
          rs[r] += pv;
          pk[nt] = (bf16_t)pv;
        }
        *(bf16x4*)&Ps[w][(qd * 4 + r) * LDP + lq * 4] = pk;
      }
      // ---- PV: 8 MFMA (P round-trip is own-wave only; lgkmcnt orders it) ----
      bf16x8 ap[2];
#pragma unroll
      for (int ks = 0; ks < 2; ++ks)
        ap[ks] = *(const bf16x8*)&Ps[w][lq * LDP + ks * 32 + qd * 8];
#pragma unroll
      for (int ks = 0; ks < 2; ++ks) {
        bf16x8 bv[4];
#pragma unroll
        for (int nt = 0; nt < 4; ++nt)
          bv[nt] = read_frag(Vt, nt * 16 + lq, ks * 4 + qd);
#pragma unroll
        for (int nt = 0; nt < 4; ++nt)
          oacc[nt] = MFMA16(ap[ks], bv[nt], oacc[nt]);
      }
    }

    // deferred row-sum reduce + O write
    float rinv[4];
#pragma unroll
    for (int r = 0; r < 4; ++r) {
      float t = rs[r];
      t += __shfl_xor(t, 1);
      t += __shfl_xor(t, 2);
      t += __shfl_xor(t, 4);
      t += __shfl_xor(t, 8);
      rinv[r] = 1.0f / t;
    }
#pragma unroll
    for (int nt = 0; nt < 4; ++nt)
#pragma unroll
      for (int r = 0; r < 4; ++r) {
        const int qg = qr + qd * 4 + r;
        O[(rowbase + qg) * E + h * 64 + nt * 16 + lq] =
            (bf16_t)(oacc[nt][r] * rinv[r]);
      }
  }
}

// ---------------------------------------------------------------------------
// launch
// ---------------------------------------------------------------------------
extern "C" void kernel_launch(void* const* d_in, const int* in_sizes, int n_in,
                              void* d_out, int out_size, void* d_ws, size_t ws_size,
                              hipStream_t stream) {
  const float* x  = (const float*)d_in[0];
  const float* Wq = (const float*)d_in[1];
  const float* bq = (const float*)d_in[2];
  const float* Wk = (const float*)d_in[3];
  const float* bk = (const float*)d_in[4];
  const float* Wv = (const float*)d_in[5];
  const float* bv = (const float*)d_in[6];
  const float* Wo = (const float*)d_in[7];
  const float* bo = (const float*)d_in[8];
  float* out = (float*)d_out;

  unsigned char* ws = (unsigned char*)d_ws;
  constexpr size_t MB = 1ull << 20;
  bf16_t* xb  = (bf16_t*)(ws + 0 * MB);   // 8 MB; reused as Ob after qkv
  bf16_t* wqb = (bf16_t*)(ws + 8 * MB);
  bf16_t* wkb = (bf16_t*)(ws + 10 * MB);
  bf16_t* wvb = (bf16_t*)(ws + 12 * MB);
  bf16_t* wob = (bf16_t*)(ws + 14 * MB);
  bf16_t* Qb  = (bf16_t*)(ws + 16 * MB);
  bf16_t* Kb  = (bf16_t*)(ws + 24 * MB);
  bf16_t* Vb  = (bf16_t*)(ws + 32 * MB);  // row-major V; dead after vtrans
  bf16_t* VT  = (bf16_t*)(ws + 40 * MB);  // [32 bh][64 d][2048 s, sigma-perm per 64]
  bf16_t* Ob  = xb;                       // xb dead after qkv
  unsigned int* counter = (unsigned int*)(ws + 32 * MB);  // overlaps dead Vb

  cvt_all_kernel<<<4096 + 4 * 1024, 256, 0, stream>>>(
      x, Wq, Wk, Wv, Wo, xb, wqb, wkb, wvb, wob);

  qkv_gemm_kernel<<<dim3(24, 32), 256, 0, stream>>>(
      xb, wqb, wkb, wvb, bq, bk, bv, Qb, Kb, Vb);

  vtrans_kernel<<<dim3(32, 32), 256, 0, stream>>>(Vb, VT);

  hipMemsetAsync(counter, 0, sizeof(unsigned int), stream);  // Vb dead now

  attn_kernel<<<768, 256, 0, stream>>>(Qb, Kb, VT, Ob, counter);

  oproj_gemm_kernel<<<dim3(8, 64), 256, 0, stream>>>(Ob, wob, bo, out);
}